// Round 1
// baseline (109.871 us; speedup 1.0000x reference)
//
#include <hip/hip_runtime.h>

// Chamfer loss: B=8, N=M=4096, C=3, fp32 in, scalar fp32 out.
// Strategy: VALU-bound brute force. Two directions, each query thread scans
// LDS-staged target segments; per-query min via register, combined across
// segments via uint-bits atomicMin (valid: distances >= 0).

constexpr int B = 8;
constexpr int N = 4096;
constexpr int M = 4096;
constexpr int S = 8;            // target segments per batch
constexpr int TM = M / S;       // 512 targets staged per block
constexpr int BLOCK = 256;
constexpr int Q = 2;            // query points per thread
constexpr int QPB = BLOCK * Q;  // 512 queries per block
constexpr int QCHUNKS = N / QPB; // 8

__global__ __launch_bounds__(256) void init_min_kernel(unsigned int* __restrict__ p, int n) {
    int i = blockIdx.x * 256 + threadIdx.x;
    if (i < n) p[i] = 0x7F800000u;  // +inf bits
}

__global__ __launch_bounds__(256) void chamfer_dir_kernel(
    const float* __restrict__ f,   // [B,N,3]
    const float* __restrict__ f_,  // [B,M,3]
    unsigned int* __restrict__ minA,   // [B*N] f->f_ mins (uint bits)
    unsigned int* __restrict__ minB)   // [B*M] f_->f mins (uint bits)
{
    __shared__ float4 sT[TM];   // padded: one ds_read_b128 broadcast per target

    const int dir = blockIdx.z;          // 0: f queries vs f_ targets; 1: swapped
    const int b   = blockIdx.y;
    const int seg = blockIdx.x % S;
    const int qc  = blockIdx.x / S;

    const float* qsrc = (dir == 0) ? f  : f_;
    const float* tsrc = (dir == 0) ? f_ : f;
    unsigned int* omin = (dir == 0) ? minA : minB;

    // ---- stage target segment into LDS (SoA->padded float4) ----
    const float* tb = tsrc + ((size_t)b * M + (size_t)seg * TM) * 3;
    for (int i = threadIdx.x; i < TM * 3; i += BLOCK) {
        int p = i / 3;
        int c = i - 3 * p;
        ((float*)&sT[p])[c] = tb[i];
    }
    __syncthreads();

    // ---- load this thread's Q query points ----
    const int q0 = qc * QPB + threadIdx.x;        // < 4096
    const int q1 = q0 + BLOCK;
    const float* qb = qsrc + (size_t)b * N * 3;
    const float q0x = qb[q0 * 3 + 0], q0y = qb[q0 * 3 + 1], q0z = qb[q0 * 3 + 2];
    const float q1x = qb[q1 * 3 + 0], q1y = qb[q1 * 3 + 1], q1z = qb[q1 * 3 + 2];

    float m0 = 3.402823466e+38f;
    float m1 = 3.402823466e+38f;

    #pragma unroll 4
    for (int m = 0; m < TM; ++m) {
        const float4 t = sT[m];
        float dx0 = q0x - t.x, dy0 = q0y - t.y, dz0 = q0z - t.z;
        float d0 = dx0 * dx0;
        d0 = fmaf(dy0, dy0, d0);
        d0 = fmaf(dz0, dz0, d0);
        m0 = fminf(m0, d0);
        float dx1 = q1x - t.x, dy1 = q1y - t.y, dz1 = q1z - t.z;
        float d1 = dx1 * dx1;
        d1 = fmaf(dy1, dy1, d1);
        d1 = fmaf(dz1, dz1, d1);
        m1 = fminf(m1, d1);
    }

    // distances >= 0 -> IEEE bits are monotone as unsigned
    atomicMin(&omin[b * N + q0], __float_as_uint(m0));
    atomicMin(&omin[b * N + q1], __float_as_uint(m1));
}

__global__ __launch_bounds__(1024) void reduce_out_kernel(
    const unsigned int* __restrict__ minA,
    const unsigned int* __restrict__ minB,
    float* __restrict__ out)
{
    __shared__ float wsum[16];
    const int tid = threadIdx.x;
    float s1 = 0.f, s2 = 0.f;
    for (int i = tid; i < B * N; i += 1024) s1 += __uint_as_float(minA[i]);
    for (int i = tid; i < B * M; i += 1024) s2 += __uint_as_float(minB[i]);
    float v = s1 * (1.0f / (B * N)) + s2 * (1.0f / (B * M));

    #pragma unroll
    for (int off = 32; off > 0; off >>= 1) v += __shfl_down(v, off, 64);
    if ((tid & 63) == 0) wsum[tid >> 6] = v;
    __syncthreads();
    if (tid < 16) {
        float w = wsum[tid];
        #pragma unroll
        for (int off = 8; off > 0; off >>= 1) w += __shfl_down(w, off, 16);
        if (tid == 0) out[0] = w;
    }
}

extern "C" void kernel_launch(void* const* d_in, const int* in_sizes, int n_in,
                              void* d_out, int out_size, void* d_ws, size_t ws_size,
                              hipStream_t stream) {
    (void)in_sizes; (void)n_in; (void)out_size; (void)ws_size;
    const float* f  = (const float*)d_in[0];
    const float* f_ = (const float*)d_in[1];
    float* out = (float*)d_out;

    unsigned int* minA = (unsigned int*)d_ws;          // B*N
    unsigned int* minB = minA + (size_t)B * N;         // B*M

    const int total = 2 * B * N;
    init_min_kernel<<<(total + 255) / 256, 256, 0, stream>>>(minA, total);

    dim3 grid(QCHUNKS * S, B, 2);   // (64, 8, 2) = 1024 blocks
    chamfer_dir_kernel<<<grid, BLOCK, 0, stream>>>(f, f_, minA, minB);

    reduce_out_kernel<<<1, 1024, 0, stream>>>(minA, minB, out);
}

// Round 2
// 101.677 us; speedup vs baseline: 1.0806x; 1.0806x over previous
//
#include <hip/hip_runtime.h>

// Chamfer loss: B=8, N=M=4096, C=3, fp32 in, scalar fp32 out.
// Round 2: packed-fp32 (v_pk_add/mul/fma via <2 x float>) inner loop.
// Issue-bound kernel -> halve instruction count by processing 2 targets
// per packed instruction. Q=4 queries/thread amortizes LDS reads.

typedef float v2f __attribute__((ext_vector_type(2)));

constexpr int B = 8;
constexpr int N = 4096;
constexpr int M = 4096;
constexpr int S = 16;            // target segments per batch
constexpr int TM = M / S;        // 256 targets staged per block
constexpr int G  = TM / 4;       // 64 groups of 4 targets
constexpr int BLOCK = 256;
constexpr int Q = 4;             // query points per thread
constexpr int QPB = BLOCK * Q;   // 1024 queries per block
constexpr int QCH = N / QPB;     // 4 query chunks

__device__ __forceinline__ v2f v2min(v2f a, v2f b) {
    v2f r;
    r.x = fminf(a.x, b.x);
    r.y = fminf(a.y, b.y);
    return r;
}

__global__ __launch_bounds__(256) void init_min_kernel(unsigned int* __restrict__ p, int n) {
    int i = blockIdx.x * 256 + threadIdx.x;
    if (i < n) p[i] = 0x7F800000u;  // +inf bits
}

__global__ __launch_bounds__(256) void chamfer_dir_kernel(
    const float* __restrict__ f,       // [B,N,3]
    const float* __restrict__ f_,      // [B,M,3]
    unsigned int* __restrict__ minA,   // [B*N] f->f_ mins (uint bits)
    unsigned int* __restrict__ minB)   // [B*M] f_->f mins (uint bits)
{
    // SoA by coordinate, 4 targets per float4 -> one ds_read_b128 (broadcast)
    // per coordinate per 4-target group.
    __shared__ float4 sX[G], sY[G], sZ[G];

    const int dir = blockIdx.z;          // 0: f queries vs f_ targets; 1: swapped
    const int b   = blockIdx.y;
    const int seg = blockIdx.x % S;
    const int qc  = blockIdx.x / S;

    const float* qsrc = (dir == 0) ? f  : f_;
    const float* tsrc = (dir == 0) ? f_ : f;
    unsigned int* omin = (dir == 0) ? minA : minB;

    // ---- stage target segment into LDS (TM == BLOCK: 1 target per thread) ----
    {
        const float* tb = tsrc + ((size_t)b * M + (size_t)seg * TM) * 3;
        const int i = threadIdx.x;     // target index within segment
        ((float*)sX)[i] = tb[3 * i + 0];
        ((float*)sY)[i] = tb[3 * i + 1];
        ((float*)sZ)[i] = tb[3 * i + 2];
    }
    __syncthreads();

    // ---- load this thread's Q query points ----
    const int qbase = qc * QPB + threadIdx.x;
    const float* qb = qsrc + (size_t)b * N * 3;
    float qx[Q], qy[Q], qz[Q];
    #pragma unroll
    for (int j = 0; j < Q; ++j) {
        const int q = qbase + j * BLOCK;
        qx[j] = qb[3 * q + 0];
        qy[j] = qb[3 * q + 1];
        qz[j] = qb[3 * q + 2];
    }

    v2f acc[Q];
    #pragma unroll
    for (int j = 0; j < Q; ++j) acc[j] = (v2f){3.402823466e+38f, 3.402823466e+38f};

    #pragma unroll 4
    for (int g = 0; g < G; ++g) {
        const float4 X = sX[g];
        const float4 Y = sY[g];
        const float4 Z = sZ[g];
        const v2f xl = {X.x, X.y}, xh = {X.z, X.w};
        const v2f yl = {Y.x, Y.y}, yh = {Y.z, Y.w};
        const v2f zl = {Z.x, Z.y}, zh = {Z.z, Z.w};

        #pragma unroll
        for (int j = 0; j < Q; ++j) {
            const v2f qxv = {qx[j], qx[j]};
            const v2f qyv = {qy[j], qy[j]};
            const v2f qzv = {qz[j], qz[j]};

            v2f dxl = qxv - xl;             // v_pk_add_f32 (neg mod)
            v2f dyl = qyv - yl;
            v2f dzl = qzv - zl;
            v2f dl  = dxl * dxl;            // v_pk_mul_f32
            dl += dyl * dyl;                // contracts -> v_pk_fma_f32
            dl += dzl * dzl;
            acc[j] = v2min(acc[j], dl);     // 2x v_min_f32

            v2f dxh = qxv - xh;
            v2f dyh = qyv - yh;
            v2f dzh = qzv - zh;
            v2f dh  = dxh * dxh;
            dh += dyh * dyh;
            dh += dzh * dzh;
            acc[j] = v2min(acc[j], dh);
        }
    }

    // distances >= 0 -> IEEE bits monotone as unsigned
    #pragma unroll
    for (int j = 0; j < Q; ++j) {
        const float m = fminf(acc[j].x, acc[j].y);
        atomicMin(&omin[b * N + qbase + j * BLOCK], __float_as_uint(m));
    }
}

__global__ __launch_bounds__(1024) void reduce_out_kernel(
    const unsigned int* __restrict__ minA,
    const unsigned int* __restrict__ minB,
    float* __restrict__ out)
{
    __shared__ float wsum[16];
    const int tid = threadIdx.x;
    float s1 = 0.f, s2 = 0.f;
    for (int i = tid; i < B * N; i += 1024) s1 += __uint_as_float(minA[i]);
    for (int i = tid; i < B * M; i += 1024) s2 += __uint_as_float(minB[i]);
    float v = s1 * (1.0f / (B * N)) + s2 * (1.0f / (B * M));

    #pragma unroll
    for (int off = 32; off > 0; off >>= 1) v += __shfl_down(v, off, 64);
    if ((tid & 63) == 0) wsum[tid >> 6] = v;
    __syncthreads();
    if (tid < 16) {
        float w = wsum[tid];
        #pragma unroll
        for (int off = 8; off > 0; off >>= 1) w += __shfl_down(w, off, 16);
        if (tid == 0) out[0] = w;
    }
}

extern "C" void kernel_launch(void* const* d_in, const int* in_sizes, int n_in,
                              void* d_out, int out_size, void* d_ws, size_t ws_size,
                              hipStream_t stream) {
    (void)in_sizes; (void)n_in; (void)out_size; (void)ws_size;
    const float* f  = (const float*)d_in[0];
    const float* f_ = (const float*)d_in[1];
    float* out = (float*)d_out;

    unsigned int* minA = (unsigned int*)d_ws;          // B*N
    unsigned int* minB = minA + (size_t)B * N;         // B*M

    const int total = 2 * B * N;
    init_min_kernel<<<(total + 255) / 256, 256, 0, stream>>>(minA, total);

    dim3 grid(QCH * S, B, 2);   // (64, 8, 2) = 1024 blocks
    chamfer_dir_kernel<<<grid, BLOCK, 0, stream>>>(f, f_, minA, minB);

    reduce_out_kernel<<<1, 1024, 0, stream>>>(minA, minB, out);
}

// Round 3
// 82.302 us; speedup vs baseline: 1.3350x; 1.2354x over previous
//
#include <hip/hip_runtime.h>

// Chamfer loss: B=8, N=M=4096, C=3, fp32 in, scalar fp32 out.
// Round 3: d = -2 q.t + ||t||^2 (+ ||q||^2 deferred per query).
//   - prep kernel: targets -> pair-interleaved {-2x0,-2x1,-2y0,-2y1,-2z0,-2z1,w0,w1}
//     + init min arrays to +inf + zero out[0].
//   - chamfer: LDS-free; wave-uniform target reads (s_load path), packed fp32:
//     3 v_pk_fma + 1 v_min3 per 2 targets per query = 2 instr/pair.
//   - reduce: 64 blocks, per-block atomicAdd (replaces single-block serial tail).

typedef float v2f __attribute__((ext_vector_type(2)));

constexpr int B = 8;
constexpr int N = 4096;
constexpr int M = 4096;
constexpr int S = 16;            // target segments per batch
constexpr int TM = M / S;        // 256 targets per segment
constexpr int GPS = TM / 2;      // 128 pair-groups per segment
constexpr int BLOCK = 256;
constexpr int Q = 4;             // query points per thread
constexpr int QPB = BLOCK * Q;   // 1024 queries per block
constexpr int QCH = N / QPB;     // 4 query chunks
constexpr int PAIRS = B * (M / 2); // 16384 pair-groups per point set

// ---- prep: transform targets, init mins, zero out ----
__global__ __launch_bounds__(256) void prep_kernel(
    const float* __restrict__ f,    // [B,N,3]
    const float* __restrict__ f_,   // [B,M,3]
    float* __restrict__ pT0,        // [PAIRS*8] from f_ (targets for dir 0)
    float* __restrict__ pT1,        // [PAIRS*8] from f  (targets for dir 1)
    unsigned int* __restrict__ minA,
    unsigned int* __restrict__ minB,
    float* __restrict__ out)
{
    const int t = blockIdx.x * 256 + threadIdx.x;   // 0 .. 2*PAIRS-1
    const int sel = t / PAIRS;                      // 0 -> f_, 1 -> f
    const int p   = t - sel * PAIRS;
    const float* src = sel ? f : f_;
    float* dst = sel ? pT1 : pT0;

    const float x0 = src[6 * p + 0], y0 = src[6 * p + 1], z0 = src[6 * p + 2];
    const float x1 = src[6 * p + 3], y1 = src[6 * p + 4], z1 = src[6 * p + 5];

    float4 r0, r1;
    r0.x = -2.0f * x0; r0.y = -2.0f * x1;
    r0.z = -2.0f * y0; r0.w = -2.0f * y1;
    r1.x = -2.0f * z0; r1.y = -2.0f * z1;
    r1.z = x0 * x0 + y0 * y0 + z0 * z0;
    r1.w = x1 * x1 + y1 * y1 + z1 * z1;
    ((float4*)dst)[2 * p]     = r0;
    ((float4*)dst)[2 * p + 1] = r1;

    // init min arrays: indices 0..B*N-1 (t < PAIRS covers half; use full t range)
    minA[t] = 0x7F800000u;   // +inf bits  (t spans exactly B*N = 32768)
    minB[t] = 0x7F800000u;

    if (t == 0) out[0] = 0.0f;
}

// ---- main pair scan ----
__global__ __launch_bounds__(256) void chamfer_dir_kernel(
    const float* __restrict__ f,
    const float* __restrict__ f_,
    const float* __restrict__ pT0,
    const float* __restrict__ pT1,
    unsigned int* __restrict__ minA,
    unsigned int* __restrict__ minB)
{
    const int dir = blockIdx.z;
    const int b   = blockIdx.y;
    const int seg = blockIdx.x % S;
    const int qc  = blockIdx.x / S;

    const float* qsrc = dir ? f_ : f;
    const float4* tp  = (const float4*)((dir ? pT1 : pT0)
                        + ((size_t)b * (M / 2) + (size_t)seg * GPS) * 8);
    unsigned int* omin = dir ? minB : minA;

    const int qbase = qc * QPB + threadIdx.x;
    const float* qb = qsrc + (size_t)b * N * 3;

    v2f qxv[Q], qyv[Q], qzv[Q];
    float qn[Q];
    #pragma unroll
    for (int j = 0; j < Q; ++j) {
        const int q = qbase + j * BLOCK;
        const float x = qb[3 * q + 0], y = qb[3 * q + 1], z = qb[3 * q + 2];
        qxv[j] = (v2f){x, x};
        qyv[j] = (v2f){y, y};
        qzv[j] = (v2f){z, z};
        qn[j] = x * x + y * y + z * z;
    }

    float m[Q];
    #pragma unroll
    for (int j = 0; j < Q; ++j) m[j] = 3.402823466e+38f;

    #pragma unroll 4
    for (int g = 0; g < GPS; ++g) {
        // wave-uniform address -> scalar loads
        const float4 r0 = tp[2 * g];
        const float4 r1 = tp[2 * g + 1];
        const v2f x01 = {r0.x, r0.y};
        const v2f y01 = {r0.z, r0.w};
        const v2f z01 = {r1.x, r1.y};
        const v2f w01 = {r1.z, r1.w};

        #pragma unroll
        for (int j = 0; j < Q; ++j) {
            v2f a = qzv[j] * z01 + w01;     // v_pk_fma_f32
            a = qyv[j] * y01 + a;           // v_pk_fma_f32
            a = qxv[j] * x01 + a;           // v_pk_fma_f32
            m[j] = fminf(fminf(m[j], a.x), a.y);   // v_min3_f32
        }
    }

    #pragma unroll
    for (int j = 0; j < Q; ++j) {
        const float d = m[j] + qn[j];   // may be ~ -1e-7 from rounding; uint-min
                                        // ordering error bounded ~1e-6, OK vs 1.4e-3
        atomicMin(&omin[b * N + qbase + j * BLOCK], __float_as_uint(d));
    }
}

// ---- parallel reduce: minA and minB are contiguous (65536 uints) ----
__global__ __launch_bounds__(256) void reduce_out_kernel(
    const unsigned int* __restrict__ mins,  // 2*B*N entries
    float* __restrict__ out)
{
    __shared__ float wsum[4];
    const int tid = threadIdx.x;
    const int idx = blockIdx.x * 256 + tid;
    float s = 0.f;
    #pragma unroll
    for (int k = 0; k < 4; ++k)            // 64 blocks * 256 thr * 4 = 65536
        s += __uint_as_float(mins[idx + k * 16384]);

    #pragma unroll
    for (int off = 32; off > 0; off >>= 1) s += __shfl_down(s, off, 64);
    if ((tid & 63) == 0) wsum[tid >> 6] = s;
    __syncthreads();
    if (tid == 0) {
        float v = (wsum[0] + wsum[1]) + (wsum[2] + wsum[3]);
        atomicAdd(out, v * (1.0f / 32768.0f));   // / (B*N), N==M
    }
}

extern "C" void kernel_launch(void* const* d_in, const int* in_sizes, int n_in,
                              void* d_out, int out_size, void* d_ws, size_t ws_size,
                              hipStream_t stream) {
    (void)in_sizes; (void)n_in; (void)out_size; (void)ws_size;
    const float* f  = (const float*)d_in[0];
    const float* f_ = (const float*)d_in[1];
    float* out = (float*)d_out;

    unsigned int* minA = (unsigned int*)d_ws;            // B*N
    unsigned int* minB = minA + (size_t)B * N;           // B*M
    float* pT0 = (float*)(minB + (size_t)B * M);         // PAIRS*8
    float* pT1 = pT0 + (size_t)PAIRS * 8;                // PAIRS*8

    prep_kernel<<<(2 * PAIRS) / 256, 256, 0, stream>>>(f, f_, pT0, pT1, minA, minB, out);

    dim3 grid(QCH * S, B, 2);   // (64, 8, 2) = 1024 blocks
    chamfer_dir_kernel<<<grid, BLOCK, 0, stream>>>(f, f_, pT0, pT1, minA, minB);

    reduce_out_kernel<<<64, 256, 0, stream>>>(minA, out);
}

// Round 4
// 81.440 us; speedup vs baseline: 1.3491x; 1.0106x over previous
//
#include <hip/hip_runtime.h>

// Chamfer loss: B=8, N=M=4096, C=3, fp32 in, scalar fp32 out.
// Round 4: no atomics anywhere hot; inline-asm v_pk_fma_f32 inner loop.
//   prep:    targets -> pair-interleaved {-2x0,-2x1,-2y0,-2y1},{-2z0,-2z1,w0,w1};
//            zeroes out[0].
//   chamfer: LDS-staged target groups (ds_read_b128 broadcast), packed fp32
//            d' = qx*x' + qy*y' + qz*z' + w (3 pk_fma / 2 targets / query),
//            v_min3 accumulate; per-(query,segment) min PLAIN-STORED to ws.
//   reduce:  min over 16 segment rows + sum; 64 blocks, one atomicAdd each.

typedef float v2f __attribute__((ext_vector_type(2)));

constexpr int B = 8;
constexpr int N = 4096;
constexpr int M = 4096;
constexpr int S = 16;             // target segments per batch
constexpr int TM = M / S;         // 256 targets per segment
constexpr int GPS = TM / 2;       // 128 pair-groups per segment
constexpr int BLOCK = 256;
constexpr int Q = 4;              // query points per thread
constexpr int QPB = BLOCK * Q;    // 1024 queries per block
constexpr int QCH = N / QPB;      // 4 query chunks
constexpr int PAIRS = B * (M / 2);  // 16384 pair-groups per point set

__device__ __forceinline__ v2f pk_fma(v2f a, v2f b, v2f c) {
    v2f d;
    asm("v_pk_fma_f32 %0, %1, %2, %3" : "=v"(d) : "v"(a), "v"(b), "v"(c));
    return d;
}

// ---- prep: transform targets; zero out[0] ----
__global__ __launch_bounds__(256) void prep_kernel(
    const float* __restrict__ f,    // [B,N,3]
    const float* __restrict__ f_,   // [B,M,3]
    float* __restrict__ pT0,        // [PAIRS*8] from f_ (targets for dir 0)
    float* __restrict__ pT1,        // [PAIRS*8] from f  (targets for dir 1)
    float* __restrict__ out)
{
    const int t = blockIdx.x * 256 + threadIdx.x;   // 0 .. 2*PAIRS-1
    const int sel = t / PAIRS;                      // 0 -> f_, 1 -> f
    const int p   = t - sel * PAIRS;
    const float* src = sel ? f : f_;
    float* dst = sel ? pT1 : pT0;

    const float x0 = src[6 * p + 0], y0 = src[6 * p + 1], z0 = src[6 * p + 2];
    const float x1 = src[6 * p + 3], y1 = src[6 * p + 4], z1 = src[6 * p + 5];

    float4 r0, r1;
    r0.x = -2.0f * x0; r0.y = -2.0f * x1;
    r0.z = -2.0f * y0; r0.w = -2.0f * y1;
    r1.x = -2.0f * z0; r1.y = -2.0f * z1;
    r1.z = x0 * x0 + y0 * y0 + z0 * z0;
    r1.w = x1 * x1 + y1 * y1 + z1 * z1;
    ((float4*)dst)[2 * p]     = r0;
    ((float4*)dst)[2 * p + 1] = r1;

    if (t == 0) out[0] = 0.0f;
}

// ---- main pair scan: plain-store per-(query,segment) mins ----
__global__ __launch_bounds__(256) void chamfer_dir_kernel(
    const float* __restrict__ f,
    const float* __restrict__ f_,
    const float* __restrict__ pT0,
    const float* __restrict__ pT1,
    float* __restrict__ ws2)          // [2*B*S*4096] partial mins
{
    __shared__ float4 sT[2 * GPS];    // 4 KB: 128 groups x {r0,r1}

    const int dir = blockIdx.z;
    const int b   = blockIdx.y;
    const int seg = blockIdx.x % S;
    const int qc  = blockIdx.x / S;

    const float* qsrc = dir ? f_ : f;
    const float4* tp4 = (const float4*)((dir ? pT1 : pT0)
                        + ((size_t)b * (M / 2) + (size_t)seg * GPS) * 8);

    // stage: one float4 per thread (coalesced, 4 KB)
    sT[threadIdx.x] = tp4[threadIdx.x];

    // load query points while staging is in flight
    const int qbase = qc * QPB + threadIdx.x;
    const float* qb = qsrc + (size_t)b * N * 3;
    v2f qxv[Q], qyv[Q], qzv[Q];
    float qn[Q];
    #pragma unroll
    for (int j = 0; j < Q; ++j) {
        const int q = qbase + j * BLOCK;
        const float x = qb[3 * q + 0], y = qb[3 * q + 1], z = qb[3 * q + 2];
        qxv[j] = (v2f){x, x};
        qyv[j] = (v2f){y, y};
        qzv[j] = (v2f){z, z};
        qn[j] = x * x + y * y + z * z;
    }
    __syncthreads();

    float m[Q];
    #pragma unroll
    for (int j = 0; j < Q; ++j) m[j] = 3.402823466e+38f;

    #pragma unroll 2
    for (int g = 0; g < GPS; ++g) {
        const float4 r0 = sT[2 * g];       // {-2x0,-2x1,-2y0,-2y1}
        const float4 r1 = sT[2 * g + 1];   // {-2z0,-2z1, w0,  w1}
        const v2f x01 = {r0.x, r0.y};
        const v2f y01 = {r0.z, r0.w};
        const v2f z01 = {r1.x, r1.y};
        const v2f w01 = {r1.z, r1.w};

        #pragma unroll
        for (int j = 0; j < Q; ++j) {
            v2f a = pk_fma(qzv[j], z01, w01);
            a = pk_fma(qyv[j], y01, a);
            a = pk_fma(qxv[j], x01, a);
            m[j] = fminf(fminf(m[j], a.x), a.y);   // v_min3_f32
        }
    }

    // plain coalesced stores: row = (dir*B + b)*S + seg, col = query
    float* row = ws2 + ((size_t)((dir * B + b) * S + seg)) * N;
    #pragma unroll
    for (int j = 0; j < Q; ++j)
        row[qbase + j * BLOCK] = m[j] + qn[j];
}

// ---- reduce: min over 16 segment rows, then mean-sum ----
__global__ __launch_bounds__(256) void reduce_out_kernel(
    const float* __restrict__ ws2,
    float* __restrict__ out)
{
    __shared__ float wsum[4];
    const int tid = threadIdx.x;
    const int t0 = blockIdx.x * 256 + tid;   // 0..16383
    float s = 0.f;
    #pragma unroll
    for (int j = 0; j < 4; ++j) {
        const int qid = t0 + j * 16384;      // 0..65535 query instances
        const int db  = qid >> 12;           // (dir*B + b) in [0,16)
        const int q   = qid & 4095;
        const float* rows = ws2 + (size_t)db * S * N + q;
        float m = rows[0];
        #pragma unroll
        for (int sgi = 1; sgi < S; ++sgi) m = fminf(m, rows[(size_t)sgi * N]);
        s += m;
    }

    #pragma unroll
    for (int off = 32; off > 0; off >>= 1) s += __shfl_down(s, off, 64);
    if ((tid & 63) == 0) wsum[tid >> 6] = s;
    __syncthreads();
    if (tid == 0) {
        const float v = (wsum[0] + wsum[1]) + (wsum[2] + wsum[3]);
        atomicAdd(out, v * (1.0f / 32768.0f));   // / (B*N), N==M
    }
}

extern "C" void kernel_launch(void* const* d_in, const int* in_sizes, int n_in,
                              void* d_out, int out_size, void* d_ws, size_t ws_size,
                              hipStream_t stream) {
    (void)in_sizes; (void)n_in; (void)out_size; (void)ws_size;
    const float* f  = (const float*)d_in[0];
    const float* f_ = (const float*)d_in[1];
    float* out = (float*)d_out;

    float* pT0 = (float*)d_ws;                       // PAIRS*8 floats
    float* pT1 = pT0 + (size_t)PAIRS * 8;            // PAIRS*8 floats
    float* ws2 = pT1 + (size_t)PAIRS * 8;            // 2*B*S*N floats (4 MB)

    prep_kernel<<<(2 * PAIRS) / 256, 256, 0, stream>>>(f, f_, pT0, pT1, out);

    dim3 grid(QCH * S, B, 2);   // (64, 8, 2) = 1024 blocks
    chamfer_dir_kernel<<<grid, BLOCK, 0, stream>>>(f, f_, pT0, pT1, ws2);

    reduce_out_kernel<<<64, 256, 0, stream>>>(ws2, out);
}

// Round 5
// 78.614 us; speedup vs baseline: 1.3976x; 1.0359x over previous
//
#include <hip/hip_runtime.h>

// Chamfer loss: B=8, N=M=4096, C=3, fp32 in, scalar fp32 out.
// Round 5: DS-pipe-bound fix. Q=8 queries/thread halves ds_read_b128 traffic
// per pair (the R4 bottleneck: 1M b128 reads ~= 20 us of per-CU DS time).
// Prep fused into chamfer's LDS staging (transform on the fly); out[0] zeroed
// by chamfer block 0 (stream-ordered before reduce). Two kernels total.

typedef float v2f __attribute__((ext_vector_type(2)));

constexpr int B = 8;
constexpr int N = 4096;
constexpr int M = 4096;
constexpr int S = 16;             // target segments per batch
constexpr int TM = M / S;         // 256 targets per segment
constexpr int GPS = TM / 2;       // 128 pair-groups per segment
constexpr int BLOCK = 256;
constexpr int Q = 8;              // query points per thread
constexpr int QPB = BLOCK * Q;    // 2048 queries per block
constexpr int QCH = N / QPB;      // 2 query chunks

__device__ __forceinline__ v2f pk_fma(v2f a, v2f b, v2f c) {
    v2f d;
    asm("v_pk_fma_f32 %0, %1, %2, %3" : "=v"(d) : "v"(a), "v"(b), "v"(c));
    return d;
}

// ---- main pair scan: transform-on-stage, plain-store per-(query,seg) mins ----
__global__ __launch_bounds__(256, 2) void chamfer_dir_kernel(
    const float* __restrict__ f,
    const float* __restrict__ f_,
    float* __restrict__ ws2,          // [2*B*S*N] partial mins
    float* __restrict__ out)
{
    // pair-interleaved: sT[2g] = {-2x0,-2x1,-2y0,-2y1}, sT[2g+1] = {-2z0,-2z1,w0,w1}
    __shared__ float4 sT[2 * GPS];    // 4 KB

    const int dir = blockIdx.z;
    const int b   = blockIdx.y;
    const int seg = blockIdx.x & (S - 1);
    const int qc  = blockIdx.x >> 4;

    const float* qsrc = dir ? f_ : f;
    const float* tsrc = dir ? f  : f_;

    if (blockIdx.x == 0 && b == 0 && dir == 0 && threadIdx.x == 0) out[0] = 0.0f;

    // ---- stage + transform: one target per thread ----
    {
        const int t = threadIdx.x;                 // target within segment
        const float* tb = tsrc + ((size_t)b * M + (size_t)seg * TM + t) * 3;
        const float x = tb[0], y = tb[1], z = tb[2];
        const int g = t >> 1, h = t & 1;
        float* base = (float*)sT;
        base[8 * g + 0 + h] = -2.0f * x;
        base[8 * g + 2 + h] = -2.0f * y;
        base[8 * g + 4 + h] = -2.0f * z;
        base[8 * g + 6 + h] = x * x + y * y + z * z;
    }

    // ---- load this thread's Q query points (overlaps staging) ----
    const int qbase = qc * QPB + threadIdx.x;
    const float* qb = qsrc + (size_t)b * N * 3;
    v2f qxv[Q], qyv[Q], qzv[Q];
    float qn[Q];
    #pragma unroll
    for (int j = 0; j < Q; ++j) {
        const int q = qbase + j * BLOCK;
        const float x = qb[3 * q + 0], y = qb[3 * q + 1], z = qb[3 * q + 2];
        qxv[j] = (v2f){x, x};
        qyv[j] = (v2f){y, y};
        qzv[j] = (v2f){z, z};
        qn[j] = x * x + y * y + z * z;
    }
    __syncthreads();

    float m[Q];
    #pragma unroll
    for (int j = 0; j < Q; ++j) m[j] = 3.402823466e+38f;

    #pragma unroll 2
    for (int g = 0; g < GPS; ++g) {
        const float4 r0 = sT[2 * g];       // {-2x0,-2x1,-2y0,-2y1}
        const float4 r1 = sT[2 * g + 1];   // {-2z0,-2z1, w0,  w1}
        const v2f x01 = {r0.x, r0.y};
        const v2f y01 = {r0.z, r0.w};
        const v2f z01 = {r1.x, r1.y};
        const v2f w01 = {r1.z, r1.w};

        #pragma unroll
        for (int j = 0; j < Q; ++j) {
            v2f a = pk_fma(qzv[j], z01, w01);
            a = pk_fma(qyv[j], y01, a);
            a = pk_fma(qxv[j], x01, a);
            m[j] = fminf(fminf(m[j], a.x), a.y);   // v_min3_f32
        }
    }

    // plain coalesced stores: row = (dir*B + b)*S + seg, col = query
    float* row = ws2 + ((size_t)((dir * B + b) * S + seg)) * N;
    #pragma unroll
    for (int j = 0; j < Q; ++j)
        row[qbase + j * BLOCK] = m[j] + qn[j];
}

// ---- reduce: min over 16 segment rows, then mean-sum ----
__global__ __launch_bounds__(256) void reduce_out_kernel(
    const float* __restrict__ ws2,
    float* __restrict__ out)
{
    __shared__ float wsum[4];
    const int tid = threadIdx.x;
    const int t0 = blockIdx.x * 256 + tid;   // 0..16383
    float s = 0.f;
    #pragma unroll
    for (int j = 0; j < 4; ++j) {
        const int qid = t0 + j * 16384;      // 0..65535 query instances
        const int db  = qid >> 12;           // (dir*B + b) in [0,16)
        const int q   = qid & 4095;
        const float* rows = ws2 + (size_t)db * S * N + q;
        float m = rows[0];
        #pragma unroll
        for (int sgi = 1; sgi < S; ++sgi) m = fminf(m, rows[(size_t)sgi * N]);
        s += m;
    }

    #pragma unroll
    for (int off = 32; off > 0; off >>= 1) s += __shfl_down(s, off, 64);
    if ((tid & 63) == 0) wsum[tid >> 6] = s;
    __syncthreads();
    if (tid == 0) {
        const float v = (wsum[0] + wsum[1]) + (wsum[2] + wsum[3]);
        atomicAdd(out, v * (1.0f / 32768.0f));   // / (B*N), N==M
    }
}

extern "C" void kernel_launch(void* const* d_in, const int* in_sizes, int n_in,
                              void* d_out, int out_size, void* d_ws, size_t ws_size,
                              hipStream_t stream) {
    (void)in_sizes; (void)n_in; (void)out_size; (void)ws_size;
    const float* f  = (const float*)d_in[0];
    const float* f_ = (const float*)d_in[1];
    float* out = (float*)d_out;

    float* ws2 = (float*)d_ws;    // 2*B*S*N floats (4 MB)

    dim3 grid(QCH * S, B, 2);     // (32, 8, 2) = 512 blocks
    chamfer_dir_kernel<<<grid, BLOCK, 0, stream>>>(f, f_, ws2, out);

    reduce_out_kernel<<<64, 256, 0, stream>>>(ws2, out);
}